// Round 5
// baseline (37.167 us; speedup 1.0000x reference)
//
#include <hip/hip_runtime.h>
#include <hip/hip_bf16.h>

// PTMLoss: loss0 + mean over upper-tri pairwise-distance terms.
// R5: m97-structure pair kernel. A-panel in registers (loaded once/block),
// B tiles double-buffered in LDS via async global_load_lds (width=16) with
// pre-swizzled global source offsets (linear LDS dest, m173 pattern).
// One barrier per tile; stage of tile J+1 overlaps compute of tile J.

#define NROWS 8192
#define DDIM  128
#define TILE  128
#define TTILES (NROWS / TILE)              // 64
#define LSTRIP 4
#define NBLKP  544                         // sum_I ceil((64-I)/4)
#define FEPS  1e-6f

typedef float f32x4 __attribute__((ext_vector_type(4)));
typedef short s16x8 __attribute__((ext_vector_type(8)));

__device__ __forceinline__ float pe_term(float d2) {
    // pe = r^3 - r^2, r = 1/sqrt(d2); lower clip -1.5 never binds (min -4/27)
    float r = rsqrtf(fmaxf(d2, 1e-30f));
    float r2 = r * r;
    return fminf(r2 * r - r2, 1000.0f);
}

__device__ __forceinline__ void gload_lds16(const void* g, void* l) {
    __builtin_amdgcn_global_load_lds(
        (const __attribute__((address_space(1))) void*)g,
        (__attribute__((address_space(3))) void*)l, 16, 0, 0);
}

// One wave per row: bf16 convert + fp32 row sum-of-squares + loss0 partial.
__global__ __launch_bounds__(256) void convert_kernel(
        const float* __restrict__ x, unsigned int* __restrict__ xb_u32,
        float* __restrict__ sq, float* __restrict__ p0) {
    int tid = threadIdx.x;
    int wave = tid >> 6, lane = tid & 63;
    int row = blockIdx.x * 4 + wave;

    float2 v = *(const float2*)(x + (size_t)row * DDIM + lane * 2);
    float s = v.x * v.x + v.y * v.y;
    float ex = v.x + FEPS, ey = v.y + FEPS;
    float e = ex * ex + ey * ey;

    __hip_bfloat16 b0 = __float2bfloat16(v.x);
    __hip_bfloat16 b1 = __float2bfloat16(v.y);
    unsigned short u0 = *reinterpret_cast<unsigned short*>(&b0);
    unsigned short u1 = *reinterpret_cast<unsigned short*>(&b1);
    xb_u32[(size_t)row * (DDIM / 2) + lane] = (unsigned)u0 | ((unsigned)u1 << 16);

    #pragma unroll
    for (int off = 32; off; off >>= 1) {
        s += __shfl_down(s, off);
        e += __shfl_down(e, off);
    }

    __shared__ float red[4];
    if (lane == 0) {
        sq[row] = s;
        float r = rsqrtf(e);
        float r2 = r * r;
        red[wave] = fminf(fmaxf(r2 * r - r2, -1.5f), 1000.0f);
    }
    __syncthreads();
    if (tid == 0) p0[blockIdx.x] = red[0] + red[1] + red[2] + red[3];
}

// pair kernel: 512 threads = 8 waves in a 4x2 grid; wave tile = 32 rows x 64 cols.
// Block = (I-panel, strip of up to 4 J-tiles).
__global__ __launch_bounds__(512, 4) void pair_kernel(
        const __hip_bfloat16* __restrict__ xb_h,
        const float* __restrict__ sq, float* __restrict__ pp) {
    const char* xb = (const char*)xb_h;
    __shared__ char smem[65536];          // B double buffer: 2 x 32 KB

    // decode blockIdx.x -> (I, j0..jend) strip
    int s = blockIdx.x, I = 0;
    int ns = (TTILES + LSTRIP - 1) / LSTRIP;
    while (s >= ns) { s -= ns; ++I; ns = (TTILES - I + LSTRIP - 1) / LSTRIP; }
    int j0 = I + s * LSTRIP;
    int jend = j0 + LSTRIP; if (jend > TTILES) jend = TTILES;

    int tid = threadIdx.x;
    int wave = tid >> 6, lane = tid & 63;
    int wR = (wave >> 1) * 32;            // 4 row-groups of 32
    int wC = (wave & 1) * 64;             // 2 col-groups of 64
    int lcol = lane & 15;
    int lrow = lane >> 4;

    // Pre-swizzled global source offsets for DMA staging (m173 pattern):
    // LDS chunk n (16B units, linear dest) must hold global chunk at
    // row*256 + ((c*16) ^ ((row&7)<<4)), row=n>>4, c=n&15. XOR is an
    // involution, so swizzled ds_read retrieves the un-swizzled element.
    int srcofs[4];
    #pragma unroll
    for (int p = 0; p < 4; ++p) {
        int n = wave * 256 + p * 64 + lane;
        int row = n >> 4, c = n & 15;
        srcofs[p] = row * 256 + ((c * 16) ^ ((row & 7) << 4));
    }

    // ---- prologue: issue DMA for first B tile into buf0 ----
    {
        const char* g = xb + (size_t)j0 * TILE * 256;
        #pragma unroll
        for (int p = 0; p < 4; ++p)
            gload_lds16(g + srcofs[p], smem + (wave * 256 + p * 64) * 16);
    }

    // ---- A-panel fragments in registers (once per block) ----
    s16x8 a[4][2];                         // [ks][frag-row]
    {
        const char* Ab = xb + ((size_t)I * TILE + wR + lcol) * 256 + lrow * 16;
        #pragma unroll
        for (int ks = 0; ks < 4; ++ks)
            #pragma unroll
            for (int r = 0; r < 2; ++r)
                a[ks][r] = *(const s16x8*)(Ab + r * 16 * 256 + ks * 64);
    }

    float sqi[2][4];
    {
        int ib = I * TILE + wR + lrow * 4;
        #pragma unroll
        for (int r = 0; r < 2; ++r)
            #pragma unroll
            for (int u = 0; u < 4; ++u) sqi[r][u] = sq[ib + r * 16 + u];
    }

    float lsum = 0.0f;
    int cur = 0;

    for (int J = j0; J < jend; ++J) {
        __syncthreads();   // drains vmcnt: buf[cur] fully staged; prev reads done

        // issue DMA for next tile into the other buffer (overlaps compute)
        if (J + 1 < jend) {
            const char* g = xb + (size_t)(J + 1) * TILE * 256;
            char* buf = smem + (cur ^ 1) * 32768;
            #pragma unroll
            for (int p = 0; p < 4; ++p)
                gload_lds16(g + srcofs[p], buf + (wave * 256 + p * 64) * 16);
        }

        // ---- MFMA from LDS B (swizzled read) x register A ----
        const char* bufc = smem + cur * 32768;
        f32x4 acc[2][4];
        #pragma unroll
        for (int r = 0; r < 2; ++r)
            #pragma unroll
            for (int c = 0; c < 4; ++c) acc[r][c] = (f32x4){0.f, 0.f, 0.f, 0.f};

        #pragma unroll
        for (int ks = 0; ks < 4; ++ks) {
            int kb = ks * 64 + lrow * 16;
            s16x8 b[4];
            #pragma unroll
            for (int c = 0; c < 4; ++c) {
                int row = wC + c * 16 + lcol;
                b[c] = *(const s16x8*)(bufc + row * 256 + (kb ^ ((row & 7) << 4)));
            }
            #pragma unroll
            for (int r = 0; r < 2; ++r)
                #pragma unroll
                for (int c = 0; c < 4; ++c)
                    acc[r][c] = __builtin_amdgcn_mfma_f32_16x16x32_bf16(
                        a[ks][r], b[c], acc[r][c], 0, 0, 0);
        }

        // ---- epilogue ----
        int jbase = J * TILE + wC + lcol;
        float sqj[4];
        #pragma unroll
        for (int c = 0; c < 4; ++c) sqj[c] = sq[jbase + c * 16];

        if (I != J) {
            #pragma unroll
            for (int r = 0; r < 2; ++r)
                #pragma unroll
                for (int u = 0; u < 4; ++u) {
                    float si = sqi[r][u];
                    #pragma unroll
                    for (int c = 0; c < 4; ++c)
                        lsum += pe_term(si + sqj[c] - 2.0f * acc[r][c][u]);
                }
        } else {
            int il0 = wR + lrow * 4;
            int jl0 = wC + lcol;
            #pragma unroll
            for (int r = 0; r < 2; ++r)
                #pragma unroll
                for (int u = 0; u < 4; ++u) {
                    int il = il0 + r * 16 + u;
                    float si = sqi[r][u];
                    #pragma unroll
                    for (int c = 0; c < 4; ++c) {
                        if (jl0 + c * 16 > il)
                            lsum += pe_term(si + sqj[c] - 2.0f * acc[r][c][u]);
                    }
                }
        }
        cur ^= 1;
    }

    // ---- block reduce (reuse smem after final barrier) ----
    #pragma unroll
    for (int off = 32; off; off >>= 1) lsum += __shfl_down(lsum, off);
    __syncthreads();
    float* red = (float*)smem;
    if (lane == 0) red[wave] = lsum;
    __syncthreads();
    if (tid == 0) {
        float t = 0.f;
        #pragma unroll
        for (int w = 0; w < 8; ++w) t += red[w];
        pp[blockIdx.x] = t;
    }
}

__global__ __launch_bounds__(1024) void reduce_kernel(
        const float* __restrict__ p0, int n0,
        const float* __restrict__ pp, int np, float* __restrict__ out) {
    int tid = threadIdx.x;
    double s0 = 0.0, sp = 0.0;
    for (int i = tid; i < n0; i += 1024) s0 += (double)p0[i];
    for (int i = tid; i < np; i += 1024) sp += (double)pp[i];
    __shared__ double sh0[1024], shp[1024];
    sh0[tid] = s0; shp[tid] = sp;
    __syncthreads();
    for (int s = 512; s; s >>= 1) {
        if (tid < s) { sh0[tid] += sh0[tid + s]; shp[tid] += shp[tid + s]; }
        __syncthreads();
    }
    if (tid == 0) {
        double cnt = (double)NROWS * (double)(NROWS - 1) * 0.5;
        out[0] = (float)(sh0[0] / (double)NROWS + shp[0] / cnt);
    }
}

extern "C" void kernel_launch(void* const* d_in, const int* in_sizes, int n_in,
                              void* d_out, int out_size, void* d_ws, size_t ws_size,
                              hipStream_t stream) {
    const float* x = (const float*)d_in[0];
    char* ws = (char*)d_ws;
    const size_t OFF_SQ = 2097152;
    const size_t OFF_P0 = OFF_SQ + 32768;
    const size_t OFF_PP = OFF_P0 + 8192;
    if (ws_size < OFF_PP + NBLKP * sizeof(float)) return;

    unsigned int* xb_u32 = (unsigned int*)ws;
    __hip_bfloat16* xb = (__hip_bfloat16*)ws;
    float* sq = (float*)(ws + OFF_SQ);
    float* p0 = (float*)(ws + OFF_P0);
    float* pp = (float*)(ws + OFF_PP);

    convert_kernel<<<NROWS / 4, 256, 0, stream>>>(x, xb_u32, sq, p0);
    pair_kernel<<<NBLKP, 512, 0, stream>>>(xb, sq, pp);
    reduce_kernel<<<1, 1024, 0, stream>>>(p0, NROWS / 4, pp, NBLKP, (float*)d_out);
}